// Round 5
// baseline (70.654 us; speedup 1.0000x reference)
//
#include <hip/hip_runtime.h>

#define FDIM 1024
#define FD4 256   // dwords per quantized row
#define BDIM 512
#define PDIM 512

__device__ __forceinline__ unsigned sad8(unsigned a, unsigned b, unsigned c) {
  return __builtin_amdgcn_sad_u8(a, b, c);  // sum_{4 bytes} |a_i - b_i| + c
}

__device__ __forceinline__ unsigned quant4(float4 v) {
  float s0 = 1.f / (1.f + __expf(-v.x));
  float s1 = 1.f / (1.f + __expf(-v.y));
  float s2 = 1.f / (1.f + __expf(-v.z));
  float s3 = 1.f / (1.f + __expf(-v.w));
  unsigned q0 = (unsigned)(s0 * 255.f + 0.5f);
  unsigned q1 = (unsigned)(s1 * 255.f + 0.5f);
  unsigned q2 = (unsigned)(s2 * 255.f + 0.5f);
  unsigned q3 = (unsigned)(s3 * 255.f + 0.5f);
  return q0 | (q1 << 8) | (q2 << 16) | (q3 << 24);
}

// Blocks 0..511: quantize one w row -> row-major wq (1 float4/thread).
// Blocks 512..575: transpose-quantize a 64-row x 32-dword x tile into
// xqT4[k4][b] (uint4-granular transpose: k4 = dword-quad index, b = x row),
// so the pair kernel can fetch x with coalesced dwordx4.
__global__ __launch_bounds__(256) void quant_kernel(
    const float* __restrict__ x, const float* __restrict__ w,
    uint4* __restrict__ xqT4, unsigned* __restrict__ wq) {
  __shared__ unsigned lt[64 * 33];
  const int tid = threadIdx.x;
  if (blockIdx.x < PDIM) {
    const int row = blockIdx.x;
    float4 v = ((const float4*)(w + (size_t)row * FDIM))[tid];
    wq[row * FD4 + tid] = quant4(v);
  } else {
    const int t = blockIdx.x - PDIM;  // 0..63
    const int r0 = (t & 7) * 64;      // b-row base (8 row-tiles)
    const int d0 = (t >> 3) * 32;     // dword-col base (8 col-tiles)
#pragma unroll
    for (int k = 0; k < 8; ++k) {
      const int flat = tid + 256 * k;  // 0..2047
      const int row = flat >> 5;       // 0..63
      const int c = flat & 31;         // 0..31
      float4 v = ((const float4*)x)[(r0 + row) * FD4 + d0 + c];
      lt[row * 33 + c] = quant4(v);
    }
    __syncthreads();
    // 512 uint4 outputs: 2 iters x 256 threads. Lanes vary b -> LDS reads are
    // 2-way bank aliased (free); global store 1KB contiguous per wave.
#pragma unroll
    for (int k = 0; k < 2; ++k) {
      const int flat = tid + 256 * k;  // 0..511
      const int dc4 = flat >> 6;       // 0..7 (uint4 col within tile)
      const int b = flat & 63;         // 0..63
      const int c = 4 * dc4;
      uint4 v;
      v.x = lt[b * 33 + c + 0];
      v.y = lt[b * 33 + c + 1];
      v.z = lt[b * 33 + c + 2];
      v.w = lt[b * 33 + c + 3];
      xqT4[(d0 / 4 + dc4) * BDIM + r0 + b] = v;
    }
  }
}

// Block: 64 b-rows (lane) x 8 p-cols; 4 waves split F (64 dwords each).
// x: 16 coalesced dwordx4 loads from uint4-transposed xqT4.
// w: 16 wave-uniform dwordx4 loads per col (readfirstlane -> scalar-eligible).
__global__ __launch_bounds__(256) void tversky_pair(
    const uint4* __restrict__ xqT4, const unsigned* __restrict__ wq,
    const float* __restrict__ bias, const float* __restrict__ alphap,
    const float* __restrict__ betap, float* __restrict__ out) {
  const int tid = threadIdx.x;
  const int lane = tid & 63;
  const int wv = __builtin_amdgcn_readfirstlane(tid >> 6);  // F-slice, uniform
  const int r = blockIdx.y * 64 + lane;  // b row
  const int c0 = blockIdx.x * 8;         // p col base

  __shared__ unsigned part[4][8][64];
  __shared__ unsigned sxp[4][64];
  __shared__ unsigned swsum[8];
  if (tid < 8) swsum[tid] = 0;
  __syncthreads();

  // x slice: 16 coalesced dwordx4 loads (lane-contiguous uint4s).
  uint4 xv[16];
#pragma unroll
  for (int j = 0; j < 16; ++j) xv[j] = xqT4[(wv * 16 + j) * BDIM + r];

  // Sx slice sum (sad vs 0 = byte sum).
  unsigned sx = 0;
#pragma unroll
  for (int j = 0; j < 16; ++j) {
    sx = sad8(xv[j].x, 0u, sx);
    sx = sad8(xv[j].y, 0u, sx);
    sx = sad8(xv[j].z, 0u, sx);
    sx = sad8(xv[j].w, 0u, sx);
  }
  sxp[wv][lane] = sx;

  // Sw for this block's 8 w rows: thread sums 8 dwords (2 uint4) of row tid>>5.
  {
    const int wrow = tid >> 5;
    const int seg = tid & 31;
    const uint4* wp = (const uint4*)wq + (c0 + wrow) * 64 + seg * 2;
    uint4 u0 = wp[0], u1 = wp[1];
    unsigned s = 0;
    s = sad8(u0.x, 0u, s); s = sad8(u0.y, 0u, s);
    s = sad8(u0.z, 0u, s); s = sad8(u0.w, 0u, s);
    s = sad8(u1.x, 0u, s); s = sad8(u1.y, 0u, s);
    s = sad8(u1.z, 0u, s); s = sad8(u1.w, 0u, s);
    atomicAdd(&swsum[wrow], s);
  }

  // Main loop: 8 cols x (16 uniform dwordx4 w-loads + 64 sads, 4 chains).
  const uint4* w4 = (const uint4*)wq;
#pragma unroll 2
  for (int pp = 0; pp < 8; ++pp) {
    const uint4* wp = w4 + (c0 + pp) * 64 + wv * 16;
    unsigned a0 = 0, a1 = 0, a2 = 0, a3 = 0;
#pragma unroll
    for (int j = 0; j < 16; ++j) {
      uint4 ww = wp[j];
      a0 = sad8(xv[j].x, ww.x, a0);
      a1 = sad8(xv[j].y, ww.y, a1);
      a2 = sad8(xv[j].z, ww.z, a2);
      a3 = sad8(xv[j].w, ww.w, a3);
    }
    part[wv][pp][lane] = a0 + a1 + a2 + a3;
  }
  __syncthreads();

  const float alpha = alphap[0];
  const float beta = betap[0];
#pragma unroll
  for (int id = tid; id < 512; id += 256) {
    const int row = id >> 3;
    const int pp = id & 7;
    const unsigned D = part[0][pp][row] + part[1][pp][row] +
                       part[2][pp][row] + part[3][pp][row];
    const unsigned Sxi = sxp[0][row] + sxp[1][row] + sxp[2][row] + sxp[3][row];
    const unsigned Swi = swsum[pp];
    const int b = blockIdx.y * 64 + row;
    const int p = c0 + pp;
    const float fSx = (float)Sxi;
    const float fSw = (float)Swi;
    const float I = 0.5f * (fSx + fSw - (float)D);
    // All terms in int units (255x real); eps scales by 255.
    const float denom = I + alpha * (fSx - I) + beta * (fSw - I) + 255.0f * 1e-8f;
    out[b * PDIM + p] = I / denom + bias[p];
  }
}

extern "C" void kernel_launch(void* const* d_in, const int* in_sizes, int n_in,
                              void* d_out, int out_size, void* d_ws, size_t ws_size,
                              hipStream_t stream) {
  const float* x = (const float*)d_in[0];
  const float* w = (const float*)d_in[1];
  const float* bias = (const float*)d_in[2];
  const float* alpha = (const float*)d_in[3];
  const float* beta = (const float*)d_in[4];
  float* out = (float*)d_out;

  unsigned char* ws = (unsigned char*)d_ws;
  uint4* xqT4 = (uint4*)ws;                      // 512 KB, [64][512] uint4
  unsigned* wq = (unsigned*)(ws + 512 * 1024);   // 512 KB, row-major [512][256]

  quant_kernel<<<dim3(PDIM + 64), dim3(256), 0, stream>>>(x, w, xqT4, wq);
  tversky_pair<<<dim3(PDIM / 8, BDIM / 64), dim3(256), 0, stream>>>(
      xqT4, wq, bias, alpha, beta, out);
}